// Round 6
// baseline (790.993 us; speedup 1.0000x reference)
//
#include <hip/hip_runtime.h>
#include <math.h>

// Problem constants
#define B_     32
#define T_     512
#define LATENT 64
#define COND   448
#define HIDDEN 1024
#define OUTD   512
#define E_     8
#define INPUT_ 512     // LATENT + COND
#define INTER_ 1536    // LATENT + COND + HIDDEN
#define GATEH  64
#define NTOK   (B_ * T_)   // 16384
#define KTAIL  64          // bias-mix folded into K as one extra BK-chunk

typedef __attribute__((ext_vector_type(8))) short short8;   // bf16x8 MFMA A/B frag
typedef __attribute__((ext_vector_type(4))) float f32x4;    // MFMA C/D frag

static __device__ __forceinline__ unsigned short f2bf(float x) {
    unsigned u = __float_as_uint(x);
    u += 0x7fffu + ((u >> 16) & 1u);
    return (unsigned short)(u >> 16);
}
static __device__ __forceinline__ float bf2f(unsigned short b) {
    return __uint_as_float((unsigned)b << 16);
}

// ---------------------------------------------------------------------------
// wprep: transpose gate weights to bf16 [n][k] rows for MFMA B-operands.
// ---------------------------------------------------------------------------
__global__ __launch_bounds__(256) void wprep_kernel(
    const float* __restrict__ gw0, const float* __restrict__ gw1,
    unsigned short* __restrict__ gw0T, unsigned short* __restrict__ gw1T)
{
    int idx = blockIdx.x * 256 + threadIdx.x;
    if (idx < GATEH * INPUT_) {
        int n = idx >> 9, k = idx & 511;
        gw0T[n * INPUT_ + k] = f2bf(gw0[k * GATEH + n]);
    } else {
        int i2 = idx - GATEH * INPUT_;
        if (i2 < GATEH * GATEH) {
            int n = i2 >> 6, k = i2 & 63;
            gw1T[n * GATEH + k] = f2bf(gw1[k * GATEH + n]);
        }
    }
}

// ---------------------------------------------------------------------------
// wtrans: w[e][i][o] fp32 -> wT[e][o][i] bf16. Tile: one expert, 256(i)x32(o).
// LDS sT[32][266] bf16: write bank-stride 133%32=5 (coprime), read b128 rows.
// ---------------------------------------------------------------------------
__global__ __launch_bounds__(256) void wtrans_kernel(
    const float* __restrict__ w, unsigned short* __restrict__ wT,
    int fin, int fout)
{
    __shared__ unsigned short sT[32][266];
    const int t = threadIdx.x;
    const int nit = fin >> 8;               // fin/256
    const int nio = nit * (fout >> 5);
    const int e = blockIdx.x / nio;
    const int rem = blockIdx.x % nio;
    const int i0 = (rem % nit) * 256;
    const int o0 = (rem / nit) * 32;
    const float* we = w + (size_t)e * fin * fout;

#pragma unroll
    for (int rr = 0; rr < 32; ++rr) {
        int idx = rr * 256 + t;
        int i = idx >> 5, o = idx & 31;
        sT[o][i] = f2bf(we[(size_t)(i0 + i) * fout + o0 + o]);
    }
    __syncthreads();

#pragma unroll
    for (int pp = 0; pp < 4; ++pp) {
        int o = pp * 8 + (t >> 5);
        int i16 = (t & 31) * 8;
        unsigned short u[8];
#pragma unroll
        for (int j = 0; j < 8; ++j) u[j] = sT[o][i16 + j];
        *(int4*)(wT + ((size_t)e * fout + o0 + o) * fin + i0 + i16) =
            *(const int4*)u;
    }
}

// ---------------------------------------------------------------------------
// Gate (MFMA): 64 tokens/block, 256 threads. Emits coef fp32, coefpad bf16
// (8 coefs + 56 zeros), xz bf16.
// ---------------------------------------------------------------------------
__global__ __launch_bounds__(256) void gate_kernel(
    const float* __restrict__ z, const float* __restrict__ c,
    const float* __restrict__ gb0,
    const float* __restrict__ gb1,
    const float* __restrict__ gw2, const float* __restrict__ gb2,
    const unsigned short* __restrict__ gw0T,
    const unsigned short* __restrict__ gw1T,
    float* __restrict__ coef, unsigned short* __restrict__ coefpad,
    unsigned short* __restrict__ xzb)
{
    __shared__ unsigned short Hb[GATEH][72];
    __shared__ float H2[GATEH][65];
    __shared__ float sLg[GATEH][E_];

    const int tid = threadIdx.x;
    const int lane = tid & 63;
    const int wv = tid >> 6;
    const int tok0 = blockIdx.x * 64;

#pragma unroll
    for (int i = 0; i < 4; ++i) {              // z: 64 tok x 64
        int idx = i * 256 + tid;
        int tr = idx >> 4, c4 = (idx & 15) * 4;
        float4 v = *(const float4*)(z + ((size_t)(tok0 + tr) * LATENT) + c4);
        ushort4 o = {f2bf(v.x), f2bf(v.y), f2bf(v.z), f2bf(v.w)};
        *(ushort4*)(xzb + (size_t)(tok0 + tr) * INPUT_ + c4) = o;
    }
#pragma unroll
    for (int i = 0; i < 28; ++i) {             // c: 64 tok x 448
        int idx = i * 256 + tid;
        int tr = idx / 112, c4 = (idx % 112) * 4;
        float4 v = *(const float4*)(c + ((size_t)(tok0 + tr) * COND) + c4);
        ushort4 o = {f2bf(v.x), f2bf(v.y), f2bf(v.z), f2bf(v.w)};
        *(ushort4*)(xzb + (size_t)(tok0 + tr) * INPUT_ + LATENT + c4) = o;
    }
    __threadfence_block();
    __syncthreads();

    const int fr = lane & 15, fq = lane >> 4;
    const int wm0 = (wv & 1) * 32, wn0 = (wv >> 1) * 32;

    f32x4 acc[2][2];
#pragma unroll
    for (int im = 0; im < 2; ++im)
#pragma unroll
        for (int in = 0; in < 2; ++in) acc[im][in] = (f32x4){0.f,0.f,0.f,0.f};

    for (int k0 = 0; k0 < INPUT_; k0 += 32) {
        short8 af[2], bf[2];
#pragma unroll
        for (int im = 0; im < 2; ++im)
            af[im] = *(const short8*)(xzb + (size_t)(tok0 + wm0 + im*16 + fr) * INPUT_
                                          + k0 + fq * 8);
#pragma unroll
        for (int in = 0; in < 2; ++in)
            bf[in] = *(const short8*)(gw0T + (size_t)(wn0 + in*16 + fr) * INPUT_
                                           + k0 + fq * 8);
#pragma unroll
        for (int im = 0; im < 2; ++im)
#pragma unroll
            for (int in = 0; in < 2; ++in)
                acc[im][in] = __builtin_amdgcn_mfma_f32_16x16x32_bf16(
                    af[im], bf[in], acc[im][in], 0, 0, 0);
    }
#pragma unroll
    for (int im = 0; im < 2; ++im)
#pragma unroll
        for (int in = 0; in < 2; ++in)
#pragma unroll
            for (int reg = 0; reg < 4; ++reg) {
                int m = wm0 + im*16 + fq*4 + reg;
                int n = wn0 + in*16 + fr;
                float h = acc[im][in][reg] + gb0[n];
                h = h > 0.f ? h : 0.01f * h;
                Hb[m][n] = f2bf(h);
            }
    __syncthreads();

    f32x4 a2[2][2];
#pragma unroll
    for (int im = 0; im < 2; ++im)
#pragma unroll
        for (int in = 0; in < 2; ++in) a2[im][in] = (f32x4){0.f,0.f,0.f,0.f};
#pragma unroll
    for (int k0 = 0; k0 < GATEH; k0 += 32) {
        short8 af[2], bf[2];
#pragma unroll
        for (int im = 0; im < 2; ++im)
            af[im] = *(const short8*)(&Hb[wm0 + im*16 + fr][k0 + fq*8]);
#pragma unroll
        for (int in = 0; in < 2; ++in)
            bf[in] = *(const short8*)(gw1T + (size_t)(wn0 + in*16 + fr) * GATEH
                                           + k0 + fq * 8);
#pragma unroll
        for (int im = 0; im < 2; ++im)
#pragma unroll
            for (int in = 0; in < 2; ++in)
                a2[im][in] = __builtin_amdgcn_mfma_f32_16x16x32_bf16(
                    af[im], bf[in], a2[im][in], 0, 0, 0);
    }
#pragma unroll
    for (int im = 0; im < 2; ++im)
#pragma unroll
        for (int in = 0; in < 2; ++in)
#pragma unroll
            for (int reg = 0; reg < 4; ++reg) {
                int m = wm0 + im*16 + fq*4 + reg;
                int n = wn0 + in*16 + fr;
                float h = a2[im][in][reg] + gb1[n];
                H2[m][n] = h > 0.f ? h : 0.01f * h;
            }
    __syncthreads();

    {
        int tok = tid >> 2, e0 = (tid & 3) * 2;
        float l0 = gb2[e0], l1 = gb2[e0 + 1];
#pragma unroll
        for (int i = 0; i < GATEH; ++i) {
            float h = H2[tok][i];
            l0 = fmaf(h, gw2[i * E_ + e0], l0);
            l1 = fmaf(h, gw2[i * E_ + e0 + 1], l1);
        }
        sLg[tok][e0] = l0; sLg[tok][e0 + 1] = l1;
    }
    __syncthreads();

    if (tid < 64) {
        int token = tok0 + tid;
        float lg[E_], m = -1e30f, s = 0.f;
#pragma unroll
        for (int e = 0; e < E_; ++e) { lg[e] = sLg[tid][e]; m = fmaxf(m, lg[e]); }
#pragma unroll
        for (int e = 0; e < E_; ++e) { lg[e] = expf(lg[e] - m); s += lg[e]; }
        float inv = 1.f / s;
        unsigned short pad[KTAIL];
#pragma unroll
        for (int e = 0; e < E_; ++e) {
            float cv = lg[e] * inv;
            coef[(size_t)token * E_ + e] = cv;
            pad[e] = f2bf(cv);
        }
#pragma unroll
        for (int j = E_; j < KTAIL; ++j) pad[j] = 0;
#pragma unroll
        for (int q = 0; q < KTAIL / 4; ++q)
            *(ushort4*)(coefpad + (size_t)token * KTAIL + q * 4) =
                *(const ushort4*)&pad[q * 4];
    }
}

// ---------------------------------------------------------------------------
// mix: wmT[b][o][i] = bf16( sum_e coef0[b][e] * wT[e][o][i] ), i<fin;
// tail rows i in [fin, fin+64): bias[e][o] (e<8) else 0.
// Fully coalesced: 1 KB runs on both wT reads and wmT writes.
// ---------------------------------------------------------------------------
__global__ __launch_bounds__(256) void mix_kernel(
    const unsigned short* __restrict__ wT,   // (E, fout, fin) bf16
    const float* __restrict__ bias,          // (E, fout) fp32
    const float* __restrict__ coef,          // (NTOK, 8)
    unsigned short* __restrict__ wmT,        // (gb, fout, fin+KTAIL) bf16
    int fin, int fout, int gb, int batch0)
{
    __shared__ float sC[B_][E_];
    const int t = threadIdx.x;
    const int fin_tot = fin + KTAIL;
    if (t < gb * E_)
        sC[t >> 3][t & 7] = coef[(size_t)(batch0 + (t >> 3)) * T_ * E_ + (t & 7)];
    __syncthreads();

    int idx = blockIdx.x * 256 + t;
    const int main_n = fout * (fin >> 3);
    if (idx < main_n) {
        const int o = idx / (fin >> 3);
        const int i8 = (idx % (fin >> 3)) * 8;
        float we[E_][8];
#pragma unroll
        for (int e = 0; e < E_; ++e) {
            int4 r = *(const int4*)(wT + ((size_t)e * fout + o) * fin + i8);
            const unsigned* p = (const unsigned*)&r;
#pragma unroll
            for (int q = 0; q < 4; ++q) {
                we[e][2*q]   = __uint_as_float(p[q] << 16);
                we[e][2*q+1] = __uint_as_float(p[q] & 0xffff0000u);
            }
        }
        for (int b = 0; b < gb; ++b) {
            float v[8];
#pragma unroll
            for (int j = 0; j < 8; ++j) v[j] = 0.f;
#pragma unroll
            for (int e = 0; e < E_; ++e) {
                float cc = sC[b][e];
#pragma unroll
                for (int j = 0; j < 8; ++j) v[j] = fmaf(cc, we[e][j], v[j]);
            }
            unsigned short u[8];
#pragma unroll
            for (int j = 0; j < 8; ++j) u[j] = f2bf(v[j]);
            *(int4*)(wmT + ((size_t)b * fout + o) * fin_tot + i8) = *(const int4*)u;
        }
    } else {
        int tix = idx - main_n;                       // tail: fout * 8 slots
        if (tix < fout * (KTAIL >> 3)) {
            const int o = tix >> 3;                   // KTAIL/8 == 8
            const int q = tix & 7;                    // which 8-chunk of 64
            unsigned short u[8];
#pragma unroll
            for (int j = 0; j < 8; ++j)
                u[j] = (q == 0) ? f2bf(bias[(size_t)j * fout + o]) : 0;
            for (int b = 0; b < gb; ++b)
                *(int4*)(wmT + ((size_t)b * fout + o) * fin_tot + fin + q * 8) =
                    *(const int4*)u;
        }
    }
}

// ---------------------------------------------------------------------------
// MFMA GEMM: 128x128 tile, BK=64, 4 waves each 64x64 (4x4 frags).
// LDS per operand: 8 chunks x [16 rows x 64 k] bf16 (chunk = ch*1024, half
// h*512). XOR bank swizzle on k-quads. XCD-aware 1D grid decode: the 4
// row-blocks sharing (col,batch) get ids congruent mod 8 -> same XCD.
// A: xz / prev / coefpad (K-tail). B: wmT[b][n][k] (bias in tail rows).
// ---------------------------------------------------------------------------
__global__ __launch_bounds__(256, 4) void gemm_kernel(
    const unsigned short* __restrict__ xz,      // (NTOK, 512) bf16
    const unsigned short* __restrict__ prev,    // (NTOK, 1024) bf16
    const unsigned short* __restrict__ wmT,     // (gb, fout, fin_tot) bf16
    const unsigned short* __restrict__ coefpad, // (NTOK, 64) bf16
    float* __restrict__ outf,                   // fp32 out (layer 4)
    unsigned short* __restrict__ outb,          // bf16 out (layers 0-3), or null
    int fin, int fout, int act, int batch0, int nx)
{
    __shared__ __align__(16) unsigned short As[128 * 64];   // 16 KB
    __shared__ __align__(16) unsigned short Bs[128 * 64];   // 16 KB

    const int tid = threadIdx.x;
    const int lane = tid & 63;
    const int wv = tid >> 6;

    // XCD-aware decode: f%8 invariant across the 4 row-blocks of one (x,z)
    {
    }
    const int f = blockIdx.x;
    const int r8 = f & 7;
    const int q8 = f >> 3;
    const int y = q8 & 3;
    const int g = (q8 >> 2) * 8 + r8;
    const int x = g % nx;
    const int zb = g / nx;

    const int fin_tot = fin + KTAIL;
    const int row0 = y * 128;
    const int col0 = x * 128;
    const size_t tokbase = (size_t)(batch0 + zb) * T_;
    const unsigned short* wmb = wmT + (size_t)zb * fin_tot * fout;

    f32x4 acc[4][4];
#pragma unroll
    for (int im = 0; im < 4; ++im)
#pragma unroll
        for (int in = 0; in < 4; ++in)
            acc[im][in] = (f32x4){0.f, 0.f, 0.f, 0.f};

    const int lrow = lane >> 2;                              // row in 16-row chunk
    const int lk8  = (((lane & 3) ^ ((lane >> 3) & 3)) * 8); // swizzled k offset
    const int wm0 = (wv & 1) * 64, wn0 = (wv >> 1) * 64;
    const int fr = lane & 15, fq = lane >> 4;
    const int koff = (fq ^ ((fr >> 1) & 3)) * 8;             // swizzled read offset

    for (int k0 = 0; k0 < fin_tot; k0 += 64) {
        __syncthreads();   // previous iteration's frag reads complete
        // A: 16 insts (ch 0..7 x h 0..1); this wave does ai = wv*4+q
#pragma unroll
        for (int q = 0; q < 4; ++q) {
            int ai = wv * 4 + q;
            int ch = ai >> 1, h = ai & 1;
            int kk = k0 + h * 32;
            const unsigned short* abase; int astr, acol;
            if (kk < INPUT_)      { abase = xz;      astr = INPUT_; acol = kk; }
            else if (kk < fin)    { abase = prev;    astr = HIDDEN; acol = kk - INPUT_; }
            else                  { abase = coefpad; astr = KTAIL;  acol = kk - fin; }
            const unsigned short* src =
                abase + (tokbase + row0 + ch * 16 + lrow) * astr + acol + lk8;
            __builtin_amdgcn_global_load_lds(
                (const __attribute__((address_space(1))) unsigned int*)(const void*)src,
                (__attribute__((address_space(3))) unsigned int*)(void*)
                    (As + ch * 1024 + h * 512),
                16, 0, 0);
        }
        // B: 16 insts
#pragma unroll
        for (int q = 0; q < 4; ++q) {
            int bi = wv * 4 + q;
            int ch = bi >> 1, h = bi & 1;
            const unsigned short* src =
                wmb + (size_t)(col0 + ch * 16 + lrow) * fin_tot + k0 + h * 32 + lk8;
            __builtin_amdgcn_global_load_lds(
                (const __attribute__((address_space(1))) unsigned int*)(const void*)src,
                (__attribute__((address_space(3))) unsigned int*)(void*)
                    (Bs + ch * 1024 + h * 512),
                16, 0, 0);
        }
        __syncthreads();   // drains vmcnt(0): staged data visible

#pragma unroll
        for (int h = 0; h < 2; ++h) {
            short8 af[4], bfv[4];
#pragma unroll
            for (int im = 0; im < 4; ++im)
                af[im] = *(const short8*)(As + ((wm0 >> 4) + im) * 1024
                                             + h * 512 + fr * 32 + koff);
#pragma unroll
            for (int in = 0; in < 4; ++in)
                bfv[in] = *(const short8*)(Bs + ((wn0 >> 4) + in) * 1024
                                              + h * 512 + fr * 32 + koff);
#pragma unroll
            for (int im = 0; im < 4; ++im)
#pragma unroll
                for (int in = 0; in < 4; ++in)
                    acc[im][in] = __builtin_amdgcn_mfma_f32_16x16x32_bf16(
                        af[im], bfv[in], acc[im][in], 0, 0, 0);
        }
    }

    // epilogue: C/D layout col=lane&15, row=quad*4+reg; leaky + store
#pragma unroll
    for (int im = 0; im < 4; ++im) {
#pragma unroll
        for (int in = 0; in < 4; ++in) {
#pragma unroll
            for (int reg = 0; reg < 4; ++reg) {
                int rr = wm0 + im * 16 + fq * 4 + reg;
                int col = wn0 + in * 16 + fr;
                float v = acc[im][in][reg];
                if (act) v = v > 0.f ? v : 0.01f * v;
                size_t off = (tokbase + row0 + rr) * fout + col0 + col;
                if (outb) outb[off] = f2bf(v);
                else      outf[off] = v;
            }
        }
    }
}

// ---------------------------------------------------------------------------
// Launch. Workspace: gw0T/gw1T 72K | wT_all 12.1M | xz 16.8M | coef 0.5M |
// cpad 2.1M | actB 33.6M (base ~65M); adaptive gb tier for wmT (+actA @32).
// ---------------------------------------------------------------------------
extern "C" void kernel_launch(void* const* d_in, const int* in_sizes, int n_in,
                              void* d_out, int out_size, void* d_ws, size_t ws_size,
                              hipStream_t stream)
{
    const float* z = (const float*)d_in[0];
    const float* c = (const float*)d_in[1];
    const float* w[5]  = {(const float*)d_in[2], (const float*)d_in[4],
                          (const float*)d_in[6], (const float*)d_in[8],
                          (const float*)d_in[10]};
    const float* bs[5] = {(const float*)d_in[3], (const float*)d_in[5],
                          (const float*)d_in[7], (const float*)d_in[9],
                          (const float*)d_in[11]};
    const float* gw0 = (const float*)d_in[12]; const float* gb0 = (const float*)d_in[13];
    const float* gw1 = (const float*)d_in[14]; const float* gb1 = (const float*)d_in[15];
    const float* gw2 = (const float*)d_in[16]; const float* gb2 = (const float*)d_in[17];

    const int fins[5]  = {INPUT_, INTER_, INTER_, INTER_, INTER_};
    const int fouts[5] = {HIDDEN, HIDDEN, HIDDEN, HIDDEN, OUTD};

    const size_t g0t_b  = (size_t)GATEH * INPUT_ * 2;
    const size_t g1t_b  = (size_t)GATEH * GATEH * 2;
    const size_t xz_b   = (size_t)NTOK * INPUT_ * 2;
    const size_t coef_b = (size_t)NTOK * E_ * 4;
    const size_t cpad_b = (size_t)NTOK * KTAIL * 2;
    const size_t act_b  = (size_t)NTOK * HIDDEN * 2;
    const size_t wmun   = (size_t)(INTER_ + KTAIL) * HIDDEN * 2;  // per-batch max

    char* p = (char*)d_ws;
    unsigned short* gw0T  = (unsigned short*)p;  p += g0t_b;
    unsigned short* gw1T  = (unsigned short*)p;  p += g1t_b;
    unsigned short* wT[5];
    for (int L = 0; L < 5; ++L) {
        wT[L] = (unsigned short*)p;
        p += (size_t)E_ * fins[L] * fouts[L] * 2;
    }
    unsigned short* xzb   = (unsigned short*)p;  p += xz_b;
    float*          coef  = (float*)p;           p += coef_b;
    unsigned short* cpad  = (unsigned short*)p;  p += cpad_b;
    unsigned short* actB  = (unsigned short*)p;  p += act_b;

    size_t base = (size_t)(p - (char*)d_ws);
    size_t avail = (ws_size > base) ? ws_size - base : 0;

    int gb;
    unsigned short* actA;
    unsigned short* wmT;
    if (avail >= act_b + 32 * wmun) {
        gb = 32; actA = (unsigned short*)p; p += act_b; wmT = (unsigned short*)p;
    } else {
        actA = (unsigned short*)d_out;
        wmT  = (unsigned short*)p;
        gb = 1;
        for (int g = 16; g >= 2; g >>= 1)
            if (avail >= (size_t)g * wmun) { gb = g; break; }
    }

    wprep_kernel<<<(GATEH * (INPUT_ + GATEH) + 255) / 256, 256, 0, stream>>>(
        gw0, gw1, gw0T, gw1T);
    for (int L = 0; L < 5; ++L) {
        int nblk = E_ * (fins[L] >> 8) * (fouts[L] >> 5);
        wtrans_kernel<<<nblk, 256, 0, stream>>>(w[L], wT[L], fins[L], fouts[L]);
    }
    gate_kernel<<<NTOK / 64, 256, 0, stream>>>(
        z, c, gb0, gb1, gw2, gb2, gw0T, gw1T, coef, cpad, xzb);

    struct L { int fin, fout, act; const unsigned short* in; unsigned short* outb; };
    L Ls[5] = {
        {INPUT_, HIDDEN, 1, actB /*unused*/, actA},
        {INTER_, HIDDEN, 1, actA, actB},
        {INTER_, HIDDEN, 1, actB, actA},
        {INTER_, HIDDEN, 1, actA, actB},
        {INTER_, OUTD,   0, actB, 0},
    };

    for (int Li = 0; Li < 5; ++Li) {
        int fin = Ls[Li].fin, fout = Ls[Li].fout;
        int mix_threads = fout * (fin >> 3) + fout * (KTAIL >> 3);
        for (int g = 0; g < B_; g += gb) {
            mix_kernel<<<(mix_threads + 255) / 256, 256, 0, stream>>>(
                wT[Li], bs[Li], coef, wmT, fin, fout, gb, g);
            int nx = fout / 128;
            gemm_kernel<<<nx * 4 * gb, 256, 0, stream>>>(
                xzb, Ls[Li].in, wmT, cpad,
                (float*)d_out, Ls[Li].outb, fin, fout, Ls[Li].act, g, nx);
        }
    }
}